// Round 8
// baseline (599.514 us; speedup 1.0000x reference)
//
#include <hip/hip_runtime.h>
#include <hip/hip_bf16.h>

// ---------------------------------------------------------------------------
// GATv2 hetero (asset/market). Only layer 1 matters (reference never feeds
// layer outputs forward). Pipeline (6 graph nodes):
//   memset(deg+cursor) -> degcount -> gemm_persist -> alloc -> fillcsr -> gather
// GEMM: persistent blocks (256 x 1024thr, 128KB LDS = Wl/Wr hi+lo staged ONCE,
// one barrier, then independent 16-row wave-chunks). Split-bf16 MFMA
// (x = hi+lo, C = Ah*Bh + Al*Bh + Ah*Bl, err ~2^-17). Swizzle (n&15)<<4:
// 16-lane column reads tile 32 banks at 2/bank (free; r7 had 8-way @ (n&7)).
// XL stored bf16 (halves gather traffic; L3-resident). XR staged in d_out.
// CSR via scan-free atomic segment allocation (segment order irrelevant).
// Gather: burst-8 edges, all loads hoisted (latency-bound diagnosis, r6/r7).
// No-max softmax: scores provably bounded (var ~0.26), exp safe in fp32.
// ---------------------------------------------------------------------------

#define NEG_SLOPE 0.2f

typedef __attribute__((ext_vector_type(8))) short short8;
typedef __attribute__((ext_vector_type(4))) float floatx4;
typedef __attribute__((ext_vector_type(4))) unsigned short us4;

// float -> bf16 bits, round-to-nearest-even (with carry)
__device__ inline unsigned short f2bf(float x) {
    union { float f; unsigned u; } v; v.f = x;
    unsigned r = v.u + 0x7FFF + ((v.u >> 16) & 1);
    return (unsigned short)(r >> 16);
}
__device__ inline float bf2f(unsigned short h) {
    union { unsigned u; float f; } v; v.u = (unsigned)h << 16;
    return v.f;
}

// ------ persistent GEMM ------------------------------------------------------
// Panels in LDS: [0]=Wl_hi [32K]=Wl_lo [64K]=Wr_hi [96K]=Wr_lo.
// Layout: row n (=output col), 256B/row (128 k * bf16), XOR-swizzled by
// (n&15)<<4 so a 16-lane column read is 2-way-per-bank (free).
__global__ __launch_bounds__(1024, 4) void gemm_persist(
        const float* __restrict__ Xa, const float* __restrict__ Xm,
        const float* __restrict__ Wl, const float* __restrict__ Wr,
        unsigned short* __restrict__ XLb, float* __restrict__ XR,
        int Na, int Nm) {
    __shared__ __align__(16) unsigned char lds[131072];

    const int t = threadIdx.x;
    // ---- stage Wl and Wr (hi/lo bf16): thread owns col n, 16 k's ----
    {
        const int n = t & 127;
        const int kh = t >> 7;                 // 0..7, k-range kh*16..+16
#pragma unroll
        for (int m = 0; m < 2; ++m) {          // 0: Wl, 1: Wr
            const float* __restrict__ W = m ? Wr : Wl;
            const int pbase = m ? 65536 : 0;
            unsigned short hb[16], lb[16];
#pragma unroll
            for (int i = 0; i < 16; ++i) {
                int k = kh * 16 + i;
                float w = W[(size_t)k * 128 + n];   // coalesced (n fast)
                unsigned short h = f2bf(w);
                hb[i] = h;
                lb[i] = f2bf(w - bf2f(h));
            }
#pragma unroll
            for (int j = 0; j < 2; ++j) {      // pack 8 k's -> one b128 write
                int koff = (kh * 16 + j * 8) * 2;
                int off = pbase + ((n * 256 + koff) ^ ((n & 15) << 4));
                short8 hv, lv;
#pragma unroll
                for (int i = 0; i < 8; ++i) { hv[i] = (short)hb[j * 8 + i]; lv[i] = (short)lb[j * 8 + i]; }
                *(short8*)(&lds[off]) = hv;
                *(short8*)(&lds[32768 + off]) = lv;
            }
        }
    }
    __syncthreads();   // the only barrier — waves independent afterwards

    const int wv = t >> 6;                     // wave 0..15
    const int l = t & 63;
    const int lr = l & 15;                     // A-row / C-col within tile
    const int lkb = (l >> 4) * 8;              // k base within 32-step
    const int nA = (Na + 15) >> 4;             // asset chunks (16 rows each)
    const int nM = (Nm + 15) >> 4;
    const int nch = nA + nM;
    const int wstride = gridDim.x * 16;

    for (int c = blockIdx.x * 16 + wv; c < nch; c += wstride) {
        const bool isA = (c < nA);
        const float* __restrict__ X = isA ? Xa : Xm;
        const int M = isA ? Na : Nm;
        const int row0 = (isA ? c : c - nA) * 16;
        const int arow = row0 + lr;

        // ---- A fragments: hi/lo for all 4 K-steps ----
        short8 ah[4], al[4];
        if (arow < M) {
#pragma unroll
            for (int ks = 0; ks < 4; ++ks) {
                const float* xp = X + (size_t)arow * 128 + ks * 32 + lkb;
                float4 f0 = *(const float4*)xp;
                float4 f1 = *(const float4*)(xp + 4);
                float xv[8] = {f0.x, f0.y, f0.z, f0.w, f1.x, f1.y, f1.z, f1.w};
                short8 h, lo;
#pragma unroll
                for (int i = 0; i < 8; ++i) {
                    unsigned short hb = f2bf(xv[i]);
                    h[i] = (short)hb;
                    lo[i] = (short)f2bf(xv[i] - bf2f(hb));
                }
                ah[ks] = h; al[ks] = lo;
            }
        } else {
#pragma unroll
            for (int ks = 0; ks < 4; ++ks) { ah[ks] = (short8)0; al[ks] = (short8)0; }
        }

        const int or0 = row0 + (l >> 4) * 4;   // C-store row base for this lane
        floatx4 acc[8];

        // ---- pass 1: Wr -> XR (both node types) ----
#pragma unroll
        for (int ct = 0; ct < 8; ++ct) acc[ct] = (floatx4)0.f;
#pragma unroll
        for (int ks = 0; ks < 4; ++ks) {
#pragma unroll
            for (int ct = 0; ct < 8; ++ct) {
                int n = ct * 16 + lr;
                int off = 65536 + ((n * 256 + (ks * 32 + lkb) * 2) ^ ((n & 15) << 4));
                short8 bh = *(const short8*)(&lds[off]);
                short8 bl = *(const short8*)(&lds[32768 + off]);
                acc[ct] = __builtin_amdgcn_mfma_f32_16x16x32_bf16(ah[ks], bh, acc[ct], 0, 0, 0);
                acc[ct] = __builtin_amdgcn_mfma_f32_16x16x32_bf16(al[ks], bh, acc[ct], 0, 0, 0);
                acc[ct] = __builtin_amdgcn_mfma_f32_16x16x32_bf16(ah[ks], bl, acc[ct], 0, 0, 0);
            }
        }
        {
            float* __restrict__ Cb = isA ? XR : (XR + (size_t)Na * 128);
#pragma unroll
            for (int ct = 0; ct < 8; ++ct) {
                int col = ct * 16 + lr;
#pragma unroll
                for (int r = 0; r < 4; ++r) {
                    int orow = or0 + r;
                    if (orow < M) Cb[(size_t)orow * 128 + col] = acc[ct][r];
                }
            }
        }

        // ---- pass 2 (asset only): Wl -> XL (bf16) ----
        if (isA) {
#pragma unroll
            for (int ct = 0; ct < 8; ++ct) acc[ct] = (floatx4)0.f;
#pragma unroll
            for (int ks = 0; ks < 4; ++ks) {
#pragma unroll
                for (int ct = 0; ct < 8; ++ct) {
                    int n = ct * 16 + lr;
                    int off = ((n * 256 + (ks * 32 + lkb) * 2) ^ ((n & 15) << 4));
                    short8 bh = *(const short8*)(&lds[off]);
                    short8 bl = *(const short8*)(&lds[32768 + off]);
                    acc[ct] = __builtin_amdgcn_mfma_f32_16x16x32_bf16(ah[ks], bh, acc[ct], 0, 0, 0);
                    acc[ct] = __builtin_amdgcn_mfma_f32_16x16x32_bf16(al[ks], bh, acc[ct], 0, 0, 0);
                    acc[ct] = __builtin_amdgcn_mfma_f32_16x16x32_bf16(ah[ks], bl, acc[ct], 0, 0, 0);
                }
            }
#pragma unroll
            for (int ct = 0; ct < 8; ++ct) {
                int col = ct * 16 + lr;
#pragma unroll
                for (int r = 0; r < 4; ++r) {
                    int orow = or0 + r;
                    if (orow < M) XLb[(size_t)orow * 128 + col] = f2bf(acc[ct][r]);
                }
            }
        }
    }
}

// ------ degree count: int4 edge reads, 4 atomics/thread ---------------------
__global__ void degcount(const int* __restrict__ aadst, const int* __restrict__ amdst,
                         int* __restrict__ deg, int Eaa, int Eam, int Na) {
    const int nqaa = Eaa >> 2, nqam = Eam >> 2;
    int i = blockIdx.x * 256 + threadIdx.x;
    if (i < nqaa) {
        int4 d = ((const int4*)aadst)[i];
        atomicAdd(&deg[d.x], 1); atomicAdd(&deg[d.y], 1);
        atomicAdd(&deg[d.z], 1); atomicAdd(&deg[d.w], 1);
    } else if (i < nqaa + nqam) {
        int4 d = ((const int4*)amdst)[i - nqaa];
        atomicAdd(&deg[Na + d.x], 1); atomicAdd(&deg[Na + d.y], 1);
        atomicAdd(&deg[Na + d.z], 1); atomicAdd(&deg[Na + d.w], 1);
    } else {                                   // scalar tails (E%4 != 0)
        int k = i - (nqaa + nqam);
        int remaa = Eaa & 3, remam = Eam & 3;
        if (k < remaa) atomicAdd(&deg[aadst[nqaa * 4 + k]], 1);
        else if (k - remaa < remam) atomicAdd(&deg[Na + amdst[nqam * 4 + k - remaa]], 1);
    }
}

// ------ scan-free segment allocation: row_start[d] = bump(cursor, deg[d]) ---
__global__ void alloc_seg(const int* __restrict__ deg, int* __restrict__ row_start,
                          int* __restrict__ fill, int* __restrict__ cursor, int N) {
    int i = blockIdx.x * 256 + threadIdx.x;
    if (i < N) {
        int d = deg[i];
        int r = atomicAdd(cursor, d);
        row_start[i] = r;
        fill[i] = r;
    }
}

// ------ CSR fill: int4 edge reads, 4 (atomic+store)/thread ------------------
__global__ void fillcsr(const int* __restrict__ aasrc, const int* __restrict__ aadst,
                        const int* __restrict__ amsrc, const int* __restrict__ amdst,
                        int* __restrict__ fill, int* __restrict__ csr,
                        int Eaa, int Eam, int Na) {
    const int nqaa = Eaa >> 2, nqam = Eam >> 2;
    int i = blockIdx.x * 256 + threadIdx.x;
    if (i < nqaa) {
        int4 sv = ((const int4*)aasrc)[i];
        int4 dv = ((const int4*)aadst)[i];
        csr[atomicAdd(&fill[dv.x], 1)] = sv.x;
        csr[atomicAdd(&fill[dv.y], 1)] = sv.y;
        csr[atomicAdd(&fill[dv.z], 1)] = sv.z;
        csr[atomicAdd(&fill[dv.w], 1)] = sv.w;
    } else if (i < nqaa + nqam) {
        int4 sv = ((const int4*)amsrc)[i - nqaa];
        int4 dv = ((const int4*)amdst)[i - nqaa];
        csr[atomicAdd(&fill[Na + dv.x], 1)] = sv.x;
        csr[atomicAdd(&fill[Na + dv.y], 1)] = sv.y;
        csr[atomicAdd(&fill[Na + dv.z], 1)] = sv.z;
        csr[atomicAdd(&fill[Na + dv.w], 1)] = sv.w;
    } else {
        int k = i - (nqaa + nqam);
        int remaa = Eaa & 3, remam = Eam & 3;
        if (k < remaa)
            csr[atomicAdd(&fill[aadst[nqaa * 4 + k]], 1)] = aasrc[nqaa * 4 + k];
        else if (k - remaa < remam)
            csr[atomicAdd(&fill[Na + amdst[nqam * 4 + k - remaa]], 1)] = amsrc[nqam * 4 + k - remaa];
    }
}

// ------ fused attention gather: 1 wave/node, burst-8 edges ------------------
__global__ __launch_bounds__(256) void gather_gat(const unsigned short* __restrict__ XLb,
                                                  const int* __restrict__ csr,
                                                  const int* __restrict__ row_start,
                                                  const int* __restrict__ deg,
                                                  const float* __restrict__ att,
                                                  const float* __restrict__ bias,
                                                  float* __restrict__ out,
                                                  int Ntot) {
    int wid = (blockIdx.x * 256 + threadIdx.x) >> 6;   // combined node id
    const int l = threadIdx.x & 63;
    if (wid >= Ntot) return;
    const int half = l >> 5;
    const int q = l & 31;                  // channel group: 4q..4q+3

    const float4 av = *(const float4*)(att + (q >> 3) * 32 + (q & 7) * 4);
    const float4 xr = *(const float4*)(out + (size_t)wid * 128 + q * 4);

    const int beg = row_start[wid];
    const int end = beg + deg[wid];
    float s = 0.f;
    float4 acc = make_float4(0.f, 0.f, 0.f, 0.f);

#define EDGE(rv, act)                                                        \
    {                                                                        \
        float x0 = bf2f(rv[0]), x1 = bf2f(rv[1]), x2 = bf2f(rv[2]), x3 = bf2f(rv[3]); \
        float z0 = x0 + xr.x; z0 = fmaxf(z0, NEG_SLOPE * z0);                \
        float z1 = x1 + xr.y; z1 = fmaxf(z1, NEG_SLOPE * z1);                \
        float z2 = x2 + xr.z; z2 = fmaxf(z2, NEG_SLOPE * z2);                \
        float z3 = x3 + xr.w; z3 = fmaxf(z3, NEG_SLOPE * z3);                \
        float p = z0 * av.x;                                                 \
        p = fmaf(z1, av.y, p);                                               \
        p = fmaf(z2, av.z, p);                                               \
        p = fmaf(z3, av.w, p);                                               \
        p += __shfl_xor(p, 1);                                               \
        p += __shfl_xor(p, 2);                                               \
        p += __shfl_xor(p, 4);                                               \
        float w = (act) ? __expf(p) : 0.f;                                   \
        s += w;                                                              \
        acc.x = fmaf(w, x0, acc.x);                                          \
        acc.y = fmaf(w, x1, acc.y);                                          \
        acc.z = fmaf(w, x2, acc.z);                                          \
        acc.w = fmaf(w, x3, acc.w);                                          \
    }

    for (int j = beg; j < end; j += 8) {
        const int b = j + half * 4;
        const bool a0 = (b + 0) < end, a1 = (b + 1) < end,
                   a2 = (b + 2) < end, a3 = (b + 3) < end;
        int s0 = csr[a0 ? b + 0 : beg];
        int s1 = csr[a1 ? b + 1 : beg];
        int s2 = csr[a2 ? b + 2 : beg];
        int s3 = csr[a3 ? b + 3 : beg];
        const us4 r0 = *(const us4*)(XLb + (size_t)s0 * 128 + q * 4);
        const us4 r1 = *(const us4*)(XLb + (size_t)s1 * 128 + q * 4);
        const us4 r2 = *(const us4*)(XLb + (size_t)s2 * 128 + q * 4);
        const us4 r3 = *(const us4*)(XLb + (size_t)s3 * 128 + q * 4);
        EDGE(r0, a0);
        EDGE(r1, a1);
        EDGE(r2, a2);
        EDGE(r3, a3);
    }
#undef EDGE

    s += __shfl_xor(s, 32);
    acc.x += __shfl_xor(acc.x, 32);
    acc.y += __shfl_xor(acc.y, 32);
    acc.z += __shfl_xor(acc.z, 32);
    acc.w += __shfl_xor(acc.w, 32);

    if (half == 0) {
        float inv = 1.f / fmaxf(s, 1e-16f);
        const float4 bv = *(const float4*)(bias + q * 4);
        float4 o = make_float4(fmaf(acc.x, inv, bv.x), fmaf(acc.y, inv, bv.y),
                               fmaf(acc.z, inv, bv.z), fmaf(acc.w, inv, bv.w));
        *(float4*)(out + (size_t)wid * 128 + q * 4) = o;
    }
}

// ---------------------------------------------------------------------------
extern "C" void kernel_launch(void* const* d_in, const int* in_sizes, int n_in,
                              void* d_out, int out_size, void* d_ws, size_t ws_size,
                              hipStream_t stream) {
    const float* x_asset  = (const float*)d_in[0];
    const float* x_market = (const float*)d_in[1];
    const int*   eaa      = (const int*)d_in[2];   // [2, Eaa]: src row, dst row
    const int*   eam      = (const int*)d_in[3];   // [2, Eam]
    const float* Wl       = (const float*)d_in[4]; // [2,128,128]
    const float* Wr       = (const float*)d_in[5];
    const float* att      = (const float*)d_in[6]; // [2,4,32]
    const float* bias     = (const float*)d_in[7]; // [2,128]

    const int Na  = in_sizes[0] / 128;
    const int Nm  = in_sizes[1] / 128;
    const int Eaa = in_sizes[2] / 2;
    const int Eam = in_sizes[3] / 2;
    const int Ntot = Na + Nm;

    // Only layer 1 matters (reference overwrites outputs each layer).
    const float* Wl1   = Wl + 128 * 128;
    const float* Wr1   = Wr + 128 * 128;
    const float* att1  = att + 128;
    const float* bias1 = bias + 128;

    // ---- workspace carve (~31MB) ----
    unsigned short* XLb = (unsigned short*)d_ws;     // Na*128 bf16 (25.6MB)
    int*   deg = (int*)(XLb + (size_t)Na * 128);     // Ntot
    int*   cursor = deg + Ntot;                      // 1  (memset'd with deg)
    int*   fill = cursor + 1;                        // Ntot
    int*   row_start = fill + Ntot;                  // Ntot
    int*   csr = row_start + Ntot;                   // E

    float* XR = (float*)d_out;                       // [Ntot,128] staged in out

    hipMemsetAsync(deg, 0, sizeof(int) * (size_t)(Ntot + 1), stream);  // deg+cursor

    const int nq = (Eaa >> 2) + (Eam >> 2) + 8;      // quads + tail headroom
    degcount<<<(nq + 255) / 256, 256, 0, stream>>>(eaa + Eaa, eam + Eam, deg, Eaa, Eam, Na);

    gemm_persist<<<256, 1024, 0, stream>>>(x_asset, x_market, Wl1, Wr1,
                                           XLb, XR, Na, Nm);

    alloc_seg<<<(Ntot + 255) / 256, 256, 0, stream>>>(deg, row_start, fill, cursor, Ntot);

    fillcsr<<<(nq + 255) / 256, 256, 0, stream>>>(eaa, eaa + Eaa, eam, eam + Eam,
                                                  fill, csr, Eaa, Eam, Na);

    gather_gat<<<(Ntot * 64 + 255) / 256, 256, 0, stream>>>(
        XLb, csr, row_start, deg, att1, bias1, (float*)d_out, Ntot);
}

// Round 9
// 384.580 us; speedup vs baseline: 1.5589x; 1.5589x over previous
//
#include <hip/hip_runtime.h>
#include <hip/hip_bf16.h>

// ---------------------------------------------------------------------------
// GATv2 hetero (asset/market). Only layer 1 matters (reference never feeds
// layer outputs forward). Pipeline (6 graph nodes):
//   memset(deg+cursor) -> degcount -> gemm_all -> alloc -> fillcsr -> gather
// GEMM: r7 structure (512thr, 64KB LDS, 2 blocks/CU; asset blocks 2-phase
// Wl->XL(bf16), Wr->XR; market blocks Wr->XR), swizzle (n&15)<<4 (r8-validated:
// SQ_LDS_BANK_CONFLICT=0). NO fused degcount (r7: serial prefix, idle GEMM).
// NO launch-bounds min-waves clamp (r8: VGPR=64 forced ~255MB spill traffic).
// Split-bf16 MFMA (x = hi+lo, C = Ah*Bh + Al*Bh + Ah*Bl, err ~2^-17).
// XL stored bf16 (halves gather traffic; L3-resident). XR staged in d_out.
// CSR via scan-free atomic segment allocation (segment order irrelevant).
// Gather: burst-8 edges, all loads hoisted (latency-bound diagnosis, r6/r7).
// No-max softmax: scores provably bounded (var ~0.26), exp safe in fp32.
// ---------------------------------------------------------------------------

#define NEG_SLOPE 0.2f

typedef __attribute__((ext_vector_type(8))) short short8;
typedef __attribute__((ext_vector_type(4))) float floatx4;
typedef __attribute__((ext_vector_type(4))) unsigned short us4;

// float -> bf16 bits, round-to-nearest-even (with carry)
__device__ inline unsigned short f2bf(float x) {
    union { float f; unsigned u; } v; v.f = x;
    unsigned r = v.u + 0x7FFF + ((v.u >> 16) & 1);
    return (unsigned short)(r >> 16);
}
__device__ inline float bf2f(unsigned short h) {
    union { unsigned u; float f; } v; v.u = (unsigned)h << 16;
    return v.f;
}

// ---- stage W^T (hi/lo bf16, swizzle (n&15)<<4) into 64KB LDS (512 thr) -----
__device__ inline void stage_w(const float* __restrict__ W, unsigned char* lds, int t) {
    const int n = t & 127;
    const int kh = t >> 7;                 // 0..3, k-range kh*32..+32
    unsigned short hb[32], lb[32];
#pragma unroll
    for (int i = 0; i < 32; ++i) {
        int k = kh * 32 + i;
        float w = W[(size_t)k * 128 + n];  // coalesced (n fast across lanes)
        unsigned short h = f2bf(w);
        hb[i] = h;
        lb[i] = f2bf(w - bf2f(h));
    }
#pragma unroll
    for (int j = 0; j < 4; ++j) {          // pack 8 k's -> one b128 write
        int koff = (kh * 32 + j * 8) * 2;
        int off = ((n * 256 + koff) ^ ((n & 15) << 4));
        short8 hv, lv;
#pragma unroll
        for (int i = 0; i < 8; ++i) { hv[i] = (short)hb[j * 8 + i]; lv[i] = (short)lb[j * 8 + i]; }
        *(short8*)(&lds[off]) = hv;
        *(short8*)(&lds[32768 + off]) = lv;
    }
}

// ---- one split-bf16 MFMA pass over the staged W (acc must be zeroed) -------
__device__ inline void mfma_pass(const unsigned char* lds, const short8* ah,
                                 const short8* al, int lr, int lkb, floatx4* acc) {
#pragma unroll
    for (int ks = 0; ks < 4; ++ks) {
#pragma unroll
        for (int ct = 0; ct < 8; ++ct) {
            int n = ct * 16 + lr;
            int off = ((n * 256 + (ks * 32 + lkb) * 2) ^ ((n & 15) << 4));
            short8 bh = *(const short8*)(&lds[off]);
            short8 bl = *(const short8*)(&lds[32768 + off]);
            acc[ct] = __builtin_amdgcn_mfma_f32_16x16x32_bf16(ah[ks], bh, acc[ct], 0, 0, 0);
            acc[ct] = __builtin_amdgcn_mfma_f32_16x16x32_bf16(al[ks], bh, acc[ct], 0, 0, 0);
            acc[ct] = __builtin_amdgcn_mfma_f32_16x16x32_bf16(ah[ks], bl, acc[ct], 0, 0, 0);
        }
    }
}

// ------ merged GEMM: asset blocks (2-phase Wl->XLbf16, Wr->XR) + market -----
// 512 threads = 8 waves; wave w owns rows blk*128 + w*16 .. +16.
__global__ __launch_bounds__(512) void gemm_all(const float* __restrict__ Xa,
                                                const float* __restrict__ Xm,
                                                const float* __restrict__ Wl,
                                                const float* __restrict__ Wr,
                                                unsigned short* __restrict__ XLb,
                                                float* __restrict__ XR,
                                                int Na, int Nm, int nblkA) {
    __shared__ __align__(16) unsigned char lds[65536];  // [0]=hi, [32768]=lo

    const int t = threadIdx.x;
    const int wv = t >> 6;                     // wave 0..7
    const int l = t & 63;
    const int lr = l & 15;                     // A-row / C-col within tile
    const int lkb = (l >> 4) * 8;              // k base within 32-step
    const bool isA = ((int)blockIdx.x < nblkA);
    const int blk = isA ? blockIdx.x : blockIdx.x - nblkA;
    const float* __restrict__ X = isA ? Xa : Xm;
    const int M = isA ? Na : Nm;
    const int arow = blk * 128 + wv * 16 + lr;

    // ---- A fragments: hi/lo for all 4 K-steps, loaded & split ONCE ----
    short8 ah[4], al[4];
    if (arow < M) {
#pragma unroll
        for (int ks = 0; ks < 4; ++ks) {
            const float* xp = X + (size_t)arow * 128 + ks * 32 + lkb;
            float4 f0 = *(const float4*)xp;
            float4 f1 = *(const float4*)(xp + 4);
            float xv[8] = {f0.x, f0.y, f0.z, f0.w, f1.x, f1.y, f1.z, f1.w};
            short8 h, lo;
#pragma unroll
            for (int i = 0; i < 8; ++i) {
                unsigned short hb = f2bf(xv[i]);
                h[i] = (short)hb;
                lo[i] = (short)f2bf(xv[i] - bf2f(hb));
            }
            ah[ks] = h; al[ks] = lo;
        }
    } else {
#pragma unroll
        for (int ks = 0; ks < 4; ++ks) { ah[ks] = (short8)0; al[ks] = (short8)0; }
    }

    const int orow0 = blk * 128 + wv * 16 + (l >> 4) * 4;
    floatx4 acc[8];

    if (isA) {
        // ---- phase 0: Wl -> XL (bf16) ----
        stage_w(Wl, lds, t);
        __syncthreads();
#pragma unroll
        for (int ct = 0; ct < 8; ++ct) acc[ct] = (floatx4)0.f;
        mfma_pass(lds, ah, al, lr, lkb, acc);
#pragma unroll
        for (int ct = 0; ct < 8; ++ct) {
            int col = ct * 16 + lr;
#pragma unroll
            for (int r = 0; r < 4; ++r) {
                int orow = orow0 + r;
                if (orow < M) XLb[(size_t)orow * 128 + col] = f2bf(acc[ct][r]);
            }
        }
        __syncthreads();                       // all ds_reads of Wl done
        // ---- phase 1: Wr -> XR (fp32, into d_out) ----
        stage_w(Wr, lds, t);
        __syncthreads();
#pragma unroll
        for (int ct = 0; ct < 8; ++ct) acc[ct] = (floatx4)0.f;
        mfma_pass(lds, ah, al, lr, lkb, acc);
#pragma unroll
        for (int ct = 0; ct < 8; ++ct) {
            int col = ct * 16 + lr;
#pragma unroll
            for (int r = 0; r < 4; ++r) {
                int orow = orow0 + r;
                if (orow < M) XR[(size_t)orow * 128 + col] = acc[ct][r];
            }
        }
    } else {
        // ---- market: Wr -> XR + Na*128 ----
        stage_w(Wr, lds, t);
        __syncthreads();
#pragma unroll
        for (int ct = 0; ct < 8; ++ct) acc[ct] = (floatx4)0.f;
        mfma_pass(lds, ah, al, lr, lkb, acc);
        float* __restrict__ XRm = XR + (size_t)Na * 128;
#pragma unroll
        for (int ct = 0; ct < 8; ++ct) {
            int col = ct * 16 + lr;
#pragma unroll
            for (int r = 0; r < 4; ++r) {
                int orow = orow0 + r;
                if (orow < M) XRm[(size_t)orow * 128 + col] = acc[ct][r];
            }
        }
    }
}

// ------ degree count: int4 edge reads, 4 atomics/thread ---------------------
__global__ void degcount(const int* __restrict__ aadst, const int* __restrict__ amdst,
                         int* __restrict__ deg, int Eaa, int Eam, int Na) {
    const int nqaa = Eaa >> 2, nqam = Eam >> 2;
    int i = blockIdx.x * 256 + threadIdx.x;
    if (i < nqaa) {
        int4 d = ((const int4*)aadst)[i];
        atomicAdd(&deg[d.x], 1); atomicAdd(&deg[d.y], 1);
        atomicAdd(&deg[d.z], 1); atomicAdd(&deg[d.w], 1);
    } else if (i < nqaa + nqam) {
        int4 d = ((const int4*)amdst)[i - nqaa];
        atomicAdd(&deg[Na + d.x], 1); atomicAdd(&deg[Na + d.y], 1);
        atomicAdd(&deg[Na + d.z], 1); atomicAdd(&deg[Na + d.w], 1);
    } else {                                   // scalar tails (E%4 != 0)
        int k = i - (nqaa + nqam);
        int remaa = Eaa & 3, remam = Eam & 3;
        if (k < remaa) atomicAdd(&deg[aadst[nqaa * 4 + k]], 1);
        else if (k - remaa < remam) atomicAdd(&deg[Na + amdst[nqam * 4 + k - remaa]], 1);
    }
}

// ------ scan-free segment allocation: row_start[d] = bump(cursor, deg[d]) ---
__global__ void alloc_seg(const int* __restrict__ deg, int* __restrict__ row_start,
                          int* __restrict__ fill, int* __restrict__ cursor, int N) {
    int i = blockIdx.x * 256 + threadIdx.x;
    if (i < N) {
        int d = deg[i];
        int r = atomicAdd(cursor, d);
        row_start[i] = r;
        fill[i] = r;
    }
}

// ------ CSR fill: int4 edge reads, 4 (atomic+store)/thread ------------------
__global__ void fillcsr(const int* __restrict__ aasrc, const int* __restrict__ aadst,
                        const int* __restrict__ amsrc, const int* __restrict__ amdst,
                        int* __restrict__ fill, int* __restrict__ csr,
                        int Eaa, int Eam, int Na) {
    const int nqaa = Eaa >> 2, nqam = Eam >> 2;
    int i = blockIdx.x * 256 + threadIdx.x;
    if (i < nqaa) {
        int4 sv = ((const int4*)aasrc)[i];
        int4 dv = ((const int4*)aadst)[i];
        csr[atomicAdd(&fill[dv.x], 1)] = sv.x;
        csr[atomicAdd(&fill[dv.y], 1)] = sv.y;
        csr[atomicAdd(&fill[dv.z], 1)] = sv.z;
        csr[atomicAdd(&fill[dv.w], 1)] = sv.w;
    } else if (i < nqaa + nqam) {
        int4 sv = ((const int4*)amsrc)[i - nqaa];
        int4 dv = ((const int4*)amdst)[i - nqaa];
        csr[atomicAdd(&fill[Na + dv.x], 1)] = sv.x;
        csr[atomicAdd(&fill[Na + dv.y], 1)] = sv.y;
        csr[atomicAdd(&fill[Na + dv.z], 1)] = sv.z;
        csr[atomicAdd(&fill[Na + dv.w], 1)] = sv.w;
    } else {
        int k = i - (nqaa + nqam);
        int remaa = Eaa & 3, remam = Eam & 3;
        if (k < remaa)
            csr[atomicAdd(&fill[aadst[nqaa * 4 + k]], 1)] = aasrc[nqaa * 4 + k];
        else if (k - remaa < remam)
            csr[atomicAdd(&fill[Na + amdst[nqam * 4 + k - remaa]], 1)] = amsrc[nqam * 4 + k - remaa];
    }
}

// ------ fused attention gather: 1 wave/node, burst-8 edges ------------------
__global__ __launch_bounds__(256) void gather_gat(const unsigned short* __restrict__ XLb,
                                                  const int* __restrict__ csr,
                                                  const int* __restrict__ row_start,
                                                  const int* __restrict__ deg,
                                                  const float* __restrict__ att,
                                                  const float* __restrict__ bias,
                                                  float* __restrict__ out,
                                                  int Ntot) {
    int wid = (blockIdx.x * 256 + threadIdx.x) >> 6;   // combined node id
    const int l = threadIdx.x & 63;
    if (wid >= Ntot) return;
    const int half = l >> 5;
    const int q = l & 31;                  // channel group: 4q..4q+3

    const float4 av = *(const float4*)(att + (q >> 3) * 32 + (q & 7) * 4);
    const float4 xr = *(const float4*)(out + (size_t)wid * 128 + q * 4);

    const int beg = row_start[wid];
    const int end = beg + deg[wid];
    float s = 0.f;
    float4 acc = make_float4(0.f, 0.f, 0.f, 0.f);

#define EDGE(rv, act)                                                        \
    {                                                                        \
        float x0 = bf2f(rv[0]), x1 = bf2f(rv[1]), x2 = bf2f(rv[2]), x3 = bf2f(rv[3]); \
        float z0 = x0 + xr.x; z0 = fmaxf(z0, NEG_SLOPE * z0);                \
        float z1 = x1 + xr.y; z1 = fmaxf(z1, NEG_SLOPE * z1);                \
        float z2 = x2 + xr.z; z2 = fmaxf(z2, NEG_SLOPE * z2);                \
        float z3 = x3 + xr.w; z3 = fmaxf(z3, NEG_SLOPE * z3);                \
        float p = z0 * av.x;                                                 \
        p = fmaf(z1, av.y, p);                                               \
        p = fmaf(z2, av.z, p);                                               \
        p = fmaf(z3, av.w, p);                                               \
        p += __shfl_xor(p, 1);                                               \
        p += __shfl_xor(p, 2);                                               \
        p += __shfl_xor(p, 4);                                               \
        float w = (act) ? __expf(p) : 0.f;                                   \
        s += w;                                                              \
        acc.x = fmaf(w, x0, acc.x);                                          \
        acc.y = fmaf(w, x1, acc.y);                                          \
        acc.z = fmaf(w, x2, acc.z);                                          \
        acc.w = fmaf(w, x3, acc.w);                                          \
    }

    for (int j = beg; j < end; j += 8) {
        const int b = j + half * 4;
        const bool a0 = (b + 0) < end, a1 = (b + 1) < end,
                   a2 = (b + 2) < end, a3 = (b + 3) < end;
        int s0 = csr[a0 ? b + 0 : beg];
        int s1 = csr[a1 ? b + 1 : beg];
        int s2 = csr[a2 ? b + 2 : beg];
        int s3 = csr[a3 ? b + 3 : beg];
        const us4 r0 = *(const us4*)(XLb + (size_t)s0 * 128 + q * 4);
        const us4 r1 = *(const us4*)(XLb + (size_t)s1 * 128 + q * 4);
        const us4 r2 = *(const us4*)(XLb + (size_t)s2 * 128 + q * 4);
        const us4 r3 = *(const us4*)(XLb + (size_t)s3 * 128 + q * 4);
        EDGE(r0, a0);
        EDGE(r1, a1);
        EDGE(r2, a2);
        EDGE(r3, a3);
    }
#undef EDGE

    s += __shfl_xor(s, 32);
    acc.x += __shfl_xor(acc.x, 32);
    acc.y += __shfl_xor(acc.y, 32);
    acc.z += __shfl_xor(acc.z, 32);
    acc.w += __shfl_xor(acc.w, 32);

    if (half == 0) {
        float inv = 1.f / fmaxf(s, 1e-16f);
        const float4 bv = *(const float4*)(bias + q * 4);
        float4 o = make_float4(fmaf(acc.x, inv, bv.x), fmaf(acc.y, inv, bv.y),
                               fmaf(acc.z, inv, bv.z), fmaf(acc.w, inv, bv.w));
        *(float4*)(out + (size_t)wid * 128 + q * 4) = o;
    }
}

// ---------------------------------------------------------------------------
extern "C" void kernel_launch(void* const* d_in, const int* in_sizes, int n_in,
                              void* d_out, int out_size, void* d_ws, size_t ws_size,
                              hipStream_t stream) {
    const float* x_asset  = (const float*)d_in[0];
    const float* x_market = (const float*)d_in[1];
    const int*   eaa      = (const int*)d_in[2];   // [2, Eaa]: src row, dst row
    const int*   eam      = (const int*)d_in[3];   // [2, Eam]
    const float* Wl       = (const float*)d_in[4]; // [2,128,128]
    const float* Wr       = (const float*)d_in[5];
    const float* att      = (const float*)d_in[6]; // [2,4,32]
    const float* bias     = (const float*)d_in[7]; // [2,128]

    const int Na  = in_sizes[0] / 128;
    const int Nm  = in_sizes[1] / 128;
    const int Eaa = in_sizes[2] / 2;
    const int Eam = in_sizes[3] / 2;
    const int Ntot = Na + Nm;

    // Only layer 1 matters (reference overwrites outputs each layer).
    const float* Wl1   = Wl + 128 * 128;
    const float* Wr1   = Wr + 128 * 128;
    const float* att1  = att + 128;
    const float* bias1 = bias + 128;

    // ---- workspace carve (~31MB) ----
    unsigned short* XLb = (unsigned short*)d_ws;     // Na*128 bf16 (25.6MB)
    int*   deg = (int*)(XLb + (size_t)Na * 128);     // Ntot
    int*   cursor = deg + Ntot;                      // 1  (memset'd with deg)
    int*   fill = cursor + 1;                        // Ntot
    int*   row_start = fill + Ntot;                  // Ntot
    int*   csr = row_start + Ntot;                   // E

    float* XR = (float*)d_out;                       // [Ntot,128] staged in out

    hipMemsetAsync(deg, 0, sizeof(int) * (size_t)(Ntot + 1), stream);  // deg+cursor

    const int nq = (Eaa >> 2) + (Eam >> 2) + 8;      // quads + tail headroom
    degcount<<<(nq + 255) / 256, 256, 0, stream>>>(eaa + Eaa, eam + Eam, deg, Eaa, Eam, Na);

    const int nblkA = (Na + 127) / 128;
    const int nblkM = (Nm + 127) / 128;
    gemm_all<<<nblkA + nblkM, 512, 0, stream>>>(x_asset, x_market, Wl1, Wr1,
                                                XLb, XR, Na, Nm, nblkA);

    alloc_seg<<<(Ntot + 255) / 256, 256, 0, stream>>>(deg, row_start, fill, cursor, Ntot);

    fillcsr<<<(nq + 255) / 256, 256, 0, stream>>>(eaa, eaa + Eaa, eam, eam + Eam,
                                                  fill, csr, Eaa, Eam, Na);

    gather_gat<<<(Ntot * 64 + 255) / 256, 256, 0, stream>>>(
        XLb, csr, row_start, deg, att1, bias1, (float*)d_out, Ntot);
}